// Round 2
// baseline (2563.082 us; speedup 1.0000x reference)
//
#include <hip/hip_runtime.h>
#include <math.h>

#define CDIM  128
#define NHEAD 8
#define DHEAD 16
#define NPAT  50000
#define NICD  591
#define NNDC  2042
#define OUTN  90
#define NEDGE 250000
#define NLAYER 2
#define EPB   128   // edges per block in seg_agg

__device__ __forceinline__ float gelu_tanh(float x) {
    float x3 = x * x * x;
    return 0.5f * x * (1.0f + tanhf(0.7978845608028654f * (x + 0.044715f * x3)));
}

// ---------------------------------------------------------------------------
// Generic fp32 GEMM: C = act(A[MxK=128] @ W[128xN] + bias), optional gelu on A
// load, optional learned-skip combine: C = a*o + (1-a)*xold, a=sigmoid(skip).
// Tile 64x64, 256 threads, 4x4 micro-tile per thread.
// ---------------------------------------------------------------------------
__global__ __launch_bounds__(256) void gemm_k128(
    const float* __restrict__ A, const float* __restrict__ W,
    const float* __restrict__ bias, float* __restrict__ Co,
    int M, int N, int gelu_in, int act,          // act: 0 none, 1 relu, 2 sigmoid
    const float* __restrict__ xold, const float* __restrict__ skipv, int skipidx)
{
    __shared__ float As[16][68];
    __shared__ float Ws[16][68];
    int bm = blockIdx.x * 64, bn = blockIdx.y * 64;
    int tl = threadIdx.x;
    int tx = tl & 15, ty = tl >> 4;
    float acc[4][4] = {};

    for (int k0 = 0; k0 < 128; k0 += 16) {
        {
            int am = tl >> 2;            // 0..63
            int ak = (tl & 3) * 4;       // 0,4,8,12
            int row = bm + am;
            float4 v = make_float4(0.f, 0.f, 0.f, 0.f);
            if (row < M) v = *(const float4*)(A + (size_t)row * 128 + k0 + ak);
            if (gelu_in) { v.x = gelu_tanh(v.x); v.y = gelu_tanh(v.y);
                           v.z = gelu_tanh(v.z); v.w = gelu_tanh(v.w); }
            As[ak + 0][am] = v.x; As[ak + 1][am] = v.y;
            As[ak + 2][am] = v.z; As[ak + 3][am] = v.w;
        }
        {
            int wk = tl >> 4;            // 0..15
            int wn = (tl & 15) * 4;      // 0..60
            int col = bn + wn;
            float4 v = make_float4(0.f, 0.f, 0.f, 0.f);
            const float* wp = W + (size_t)(k0 + wk) * N;
            if (((N & 3) == 0) && (col + 3) < N) {
                v = *(const float4*)(wp + col);
            } else {
                if (col     < N) v.x = wp[col];
                if (col + 1 < N) v.y = wp[col + 1];
                if (col + 2 < N) v.z = wp[col + 2];
                if (col + 3 < N) v.w = wp[col + 3];
            }
            Ws[wk][wn] = v.x; Ws[wk][wn + 1] = v.y;
            Ws[wk][wn + 2] = v.z; Ws[wk][wn + 3] = v.w;
        }
        __syncthreads();
        #pragma unroll
        for (int kk = 0; kk < 16; kk++) {
            float4 av = *(const float4*)&As[kk][ty * 4];
            float4 wv = *(const float4*)&Ws[kk][tx * 4];
            float a_[4] = {av.x, av.y, av.z, av.w};
            float w_[4] = {wv.x, wv.y, wv.z, wv.w};
            #pragma unroll
            for (int i = 0; i < 4; i++)
                #pragma unroll
                for (int j = 0; j < 4; j++)
                    acc[i][j] += a_[i] * w_[j];
        }
        __syncthreads();
    }

    float aSk = 0.f, oneM = 0.f;
    if (skipv) {
        float sv = skipv[skipidx];
        aSk = 1.0f / (1.0f + expf(-sv));
        oneM = 1.0f - aSk;
    }
    for (int i = 0; i < 4; i++) {
        int row = bm + ty * 4 + i;
        if (row >= M) break;
        for (int j = 0; j < 4; j++) {
            int col = bn + tx * 4 + j;
            if (col >= N) continue;
            float v = acc[i][j] + (bias ? bias[col] : 0.f);
            if (act == 1) v = fmaxf(v, 0.f);
            else if (act == 2) v = 1.0f / (1.0f + expf(-v));
            if (skipv) v = aSk * v + oneM * xold[(size_t)row * N + col];
            Co[(size_t)row * N + col] = v;
        }
    }
}

// ---------------------------------------------------------------------------
// CSR build: histogram, single-block exclusive scan, scatter
// ---------------------------------------------------------------------------
__global__ void hist_kernel(const int* __restrict__ dst, int* __restrict__ deg) {
    int t = blockIdx.x * blockDim.x + threadIdx.x;
    if (t < NEDGE) atomicAdd(&deg[dst[t]], 1);
}

__global__ __launch_bounds__(1024) void exscan_kernel(
    const int* __restrict__ in, int* __restrict__ out, int n)
{
    __shared__ int part[1024];
    int t = threadIdx.x;
    int per = (n + 1023) >> 10;
    int s0 = t * per, s1 = min(s0 + per, n);
    int s = 0;
    for (int i = s0; i < s1; i++) s += in[i];
    part[t] = s;
    __syncthreads();
    for (int off = 1; off < 1024; off <<= 1) {
        int v = (t >= off) ? part[t - off] : 0;
        __syncthreads();
        part[t] += v;
        __syncthreads();
    }
    int run = (t == 0) ? 0 : part[t - 1];
    for (int i = s0; i < s1; i++) { out[i] = run; run += in[i]; }
    if (t == 1023) out[n] = part[1023];
}

__global__ void scatter_kernel(const int* __restrict__ dst,
                               int* __restrict__ cursor, int* __restrict__ elist) {
    int t = blockIdx.x * blockDim.x + threadIdx.x;
    if (t < NEDGE) { int p = atomicAdd(&cursor[dst[t]], 1); elist[p] = t; }
}

// ---------------------------------------------------------------------------
// x = relu(emb[idx]) gather
// ---------------------------------------------------------------------------
__global__ void gather_relu_kernel(const float* __restrict__ emb,
                                   const int* __restrict__ idx,
                                   float* __restrict__ out, int n) {
    int t = blockIdx.x * blockDim.x + threadIdx.x;
    if (t < n * CDIM) {
        int r = t >> 7, c = t & 127;
        out[t] = fmaxf(emb[(size_t)idx[r] * CDIM + c], 0.f);
    }
}

// ---------------------------------------------------------------------------
// kr[n,h,e] = sum_d k[n,h,d] * arel[h,d,e]   (per-head 16x16 transform)
// ---------------------------------------------------------------------------
__global__ __launch_bounds__(128) void rel_transform_kernel(
    const float* __restrict__ kin, const float* __restrict__ arel,
    float* __restrict__ kout, int n)
{
    __shared__ float aS[NHEAD * DHEAD * DHEAD];   // 2048
    __shared__ float rowS[CDIM];
    int t = threadIdx.x;
    for (int i = t; i < NHEAD * DHEAD * DHEAD; i += 128) aS[i] = arel[i];
    __syncthreads();
    int h = t >> 4, e = t & 15;
    const float* ah = &aS[h * 256];
    for (int row = blockIdx.x; row < n; row += gridDim.x) {
        rowS[t] = kin[(size_t)row * CDIM + t];
        __syncthreads();
        float acc = 0.f;
        #pragma unroll
        for (int dd = 0; dd < 16; ++dd) acc += rowS[h * 16 + dd] * ah[dd * 16 + e];
        kout[(size_t)row * CDIM + t] = acc;
        __syncthreads();
    }
}

// ---------------------------------------------------------------------------
// alpha[e,h] = (q[dst[e],h,:] . kr[src[e],h,:]) * p_rel[h] * (1/sqrt(D))
// ---------------------------------------------------------------------------
__global__ __launch_bounds__(256) void edge_logits_kernel(
    const int* __restrict__ src, const int* __restrict__ dst,
    const float* __restrict__ q, const float* __restrict__ kr,
    const float* __restrict__ prel, float* __restrict__ alpha)
{
    int t = blockIdx.x * blockDim.x + threadIdx.x;
    if (t >= NEDGE * NHEAD) return;
    int e = t >> 3, h = t & 7;
    const float4* qp = (const float4*)(q  + (size_t)dst[e] * CDIM + h * DHEAD);
    const float4* kp = (const float4*)(kr + (size_t)src[e] * CDIM + h * DHEAD);
    float acc = 0.f;
    #pragma unroll
    for (int i = 0; i < 4; i++) {
        float4 a = qp[i], b = kp[i];
        acc += a.x * b.x + a.y * b.y + a.z * b.z + a.w * b.w;
    }
    alpha[t] = acc * prel[h] * 0.25f;
}

// ---------------------------------------------------------------------------
// Segment softmax stats: one WAVE per (dst,head). Lanes stride the dst's CSR
// edge range; shuffle-reduce max then exp-sum. stats[(d*8+h)] = {m, 1/s}.
// ---------------------------------------------------------------------------
__global__ __launch_bounds__(256) void seg_stats_kernel(
    const int* __restrict__ rowptr, const int* __restrict__ elist,
    const float* __restrict__ alpha, float* __restrict__ stats, int nd)
{
    int wid = (blockIdx.x * 256 + threadIdx.x) >> 6;   // global wave id
    int lane = threadIdx.x & 63;
    if (wid >= nd * NHEAD) return;
    int d = wid >> 3, h = wid & 7;
    int r0 = rowptr[d], r1 = rowptr[d + 1];
    float mx = -1e30f;
    for (int i = r0 + lane; i < r1; i += 64)
        mx = fmaxf(mx, alpha[(size_t)elist[i] * NHEAD + h]);
    #pragma unroll
    for (int o = 32; o; o >>= 1) mx = fmaxf(mx, __shfl_xor(mx, o));
    float sm = 0.f;
    for (int i = r0 + lane; i < r1; i += 64)
        sm += expf(alpha[(size_t)elist[i] * NHEAD + h] - mx);
    #pragma unroll
    for (int o = 32; o; o >>= 1) sm += __shfl_xor(sm, o);
    if (lane == 0) {
        stats[(size_t)wid * 2]     = mx;
        stats[(size_t)wid * 2 + 1] = (sm > 0.f) ? 1.0f / sm : 0.f;
    }
}

// ---------------------------------------------------------------------------
// Edge-chunk-parallel weighted segment sum. Each block takes EPB consecutive
// entries of the dst-sorted elist; staging threads compute normalized softmax
// weights (exp fused); 128 channel-threads accumulate per dst-run and flush
// with atomicAdd at run boundaries (few per chunk).
// ---------------------------------------------------------------------------
__global__ __launch_bounds__(128) void seg_agg_kernel(
    const int* __restrict__ elist, const int* __restrict__ src,
    const int* __restrict__ dstarr, const float* __restrict__ alpha,
    const float* __restrict__ stats, const float* __restrict__ vr,
    float* __restrict__ agg, int ne)
{
    __shared__ int   sSrc[EPB];
    __shared__ int   sDst[EPB];
    __shared__ float sW[EPB][NHEAD];
    int i0 = blockIdx.x * EPB;
    int t  = threadIdx.x;
    int cnt = min(EPB, ne - i0);
    if (t < cnt) {
        int e = elist[i0 + t];
        sSrc[t] = src[e];
        int d = dstarr[e];
        sDst[t] = d;
        #pragma unroll
        for (int h = 0; h < NHEAD; h++) {
            float m  = stats[((size_t)d * NHEAD + h) * 2];
            float si = stats[((size_t)d * NHEAD + h) * 2 + 1];
            sW[t][h] = expf(alpha[(size_t)e * NHEAD + h] - m) * si;
        }
    }
    __syncthreads();
    int h = t >> 4;
    float acc = 0.f;
    int curd = sDst[0];
    for (int i = 0; i < cnt; i++) {
        int d = sDst[i];
        if (d != curd) {
            atomicAdd(&agg[(size_t)curd * CDIM + t], acc);
            acc = 0.f;
            curd = d;
        }
        acc += vr[(size_t)sSrc[i] * CDIM + t] * sW[i][h];
    }
    atomicAdd(&agg[(size_t)curd * CDIM + t], acc);
}

// ---------------------------------------------------------------------------
extern "C" void kernel_launch(void* const* d_in, const int* in_sizes, int n_in,
                              void* d_out, int out_size, void* d_ws, size_t ws_size,
                              hipStream_t stream)
{
    const float* x_patient = (const float*)d_in[0];
    const float* w_in      = (const float*)d_in[1];
    const float* b_in      = (const float*)d_in[2];
    const float* emb_icd   = (const float*)d_in[3];
    const float* emb_ndc   = (const float*)d_in[4];
    const float* kw        = (const float*)d_in[5];
    const float* kbias     = (const float*)d_in[6];
    const float* qw        = (const float*)d_in[7];
    const float* qbias     = (const float*)d_in[8];
    const float* vw        = (const float*)d_in[9];
    const float* vbias     = (const float*)d_in[10];
    const float* aw        = (const float*)d_in[11];
    const float* abias     = (const float*)d_in[12];
    const float* skip      = (const float*)d_in[13];
    const float* a_rel     = (const float*)d_in[14];
    const float* m_rel     = (const float*)d_in[15];
    const float* p_rel     = (const float*)d_in[16];
    const float* w_out     = (const float*)d_in[17];
    const float* b_out     = (const float*)d_in[18];
    const int*   x_icd     = (const int*)d_in[19];
    const int*   x_ndc     = (const int*)d_in[20];
    const int* esrc[4] = {(const int*)d_in[21], (const int*)d_in[23],
                          (const int*)d_in[25], (const int*)d_in[27]};
    const int* edst[4] = {(const int*)d_in[22], (const int*)d_in[24],
                          (const int*)d_in[26], (const int*)d_in[28]};

    const int st_[4] = {0, 1, 0, 2};
    const int dt_[4] = {1, 0, 2, 0};
    const int sizes[3] = {NPAT, NICD, NNDC};

    char* p = (char*)d_ws;
    auto alloc = [&](size_t bytes) -> void* {
        void* r = (void*)p;
        p += (bytes + 255) & ~(size_t)255;
        return r;
    };

    float *x[3], *kbuf[3], *qbuf[3], *vbuf[3];
    for (int t = 0; t < 3; t++) x[t]    = (float*)alloc((size_t)sizes[t] * CDIM * 4);
    for (int t = 0; t < 3; t++) kbuf[t] = (float*)alloc((size_t)sizes[t] * CDIM * 4);
    for (int t = 0; t < 3; t++) qbuf[t] = (float*)alloc((size_t)sizes[t] * CDIM * 4);
    for (int t = 0; t < 3; t++) vbuf[t] = (float*)alloc((size_t)sizes[t] * CDIM * 4);
    float* aggbase = (float*)alloc((size_t)(NPAT + NICD + NNDC) * CDIM * 4);
    float* agg[3];
    agg[0] = aggbase;
    agg[1] = aggbase + (size_t)NPAT * CDIM;
    agg[2] = agg[1] + (size_t)NICD * CDIM;
    float* krbuf    = (float*)alloc((size_t)NPAT * CDIM * 4);
    float* vrbuf    = (float*)alloc((size_t)NPAT * CDIM * 4);
    float* alphabuf = (float*)alloc((size_t)NEDGE * NHEAD * 4);
    float* statsbuf = (float*)alloc((size_t)NPAT * NHEAD * 2 * 4);
    int *rowptr[4], *elist[4];
    for (int r = 0; r < 4; r++) {
        rowptr[r] = (int*)alloc((size_t)(sizes[dt_[r]] + 1) * 4);
        elist[r]  = (int*)alloc((size_t)NEDGE * 4);
    }
    int* deg    = (int*)alloc((size_t)NPAT * 4);
    int* cursor = (int*)alloc((size_t)NPAT * 4);

    auto gemm = [&](const float* A, const float* W, const float* bias, float* Co,
                    int M, int N, int gelu_in, int act,
                    const float* xold, const float* skipv, int skipidx) {
        dim3 grid((M + 63) / 64, (N + 63) / 64);
        gemm_k128<<<grid, dim3(256), 0, stream>>>(A, W, bias, Co, M, N,
                                                  gelu_in, act, xold, skipv, skipidx);
    };

    // ---- CSR build (by dst), once per launch, reused by both layers ----
    for (int r = 0; r < 4; r++) {
        int nd = sizes[dt_[r]];
        hipMemsetAsync(deg, 0, (size_t)nd * 4, stream);
        hist_kernel<<<(NEDGE + 255) / 256, 256, 0, stream>>>(edst[r], deg);
        exscan_kernel<<<1, 1024, 0, stream>>>(deg, rowptr[r], nd);
        hipMemcpyAsync(cursor, rowptr[r], (size_t)nd * 4,
                       hipMemcpyDeviceToDevice, stream);
        scatter_kernel<<<(NEDGE + 255) / 256, 256, 0, stream>>>(edst[r], cursor, elist[r]);
    }

    // ---- input projections ----
    gemm(x_patient, w_in, b_in, x[0], NPAT, 128, 0, 1, nullptr, nullptr, 0);
    gather_relu_kernel<<<(NICD * CDIM + 255) / 256, 256, 0, stream>>>(emb_icd, x_icd, x[1], NICD);
    gather_relu_kernel<<<(NNDC * CDIM + 255) / 256, 256, 0, stream>>>(emb_ndc, x_ndc, x[2], NNDC);

    // ---- layers ----
    for (int l = 0; l < NLAYER; l++) {
        for (int t = 0; t < 3; t++) {
            int wi = l * 3 + t;
            gemm(x[t], kw + (size_t)wi * 16384, kbias + (size_t)wi * 128,
                 kbuf[t], sizes[t], 128, 0, 0, nullptr, nullptr, 0);
            gemm(x[t], qw + (size_t)wi * 16384, qbias + (size_t)wi * 128,
                 qbuf[t], sizes[t], 128, 0, 0, nullptr, nullptr, 0);
            gemm(x[t], vw + (size_t)wi * 16384, vbias + (size_t)wi * 128,
                 vbuf[t], sizes[t], 128, 0, 0, nullptr, nullptr, 0);
        }
        hipMemsetAsync(aggbase, 0, (size_t)(NPAT + NICD + NNDC) * CDIM * 4, stream);
        for (int r = 0; r < 4; r++) {
            int s = st_[r], d = dt_[r];
            int ns = sizes[s], nd = sizes[d];
            int grid_rt = ns < 2048 ? ns : 2048;
            rel_transform_kernel<<<grid_rt, 128, 0, stream>>>(
                kbuf[s], a_rel + (size_t)(l * 4 + r) * 2048, krbuf, ns);
            rel_transform_kernel<<<grid_rt, 128, 0, stream>>>(
                vbuf[s], m_rel + (size_t)(l * 4 + r) * 2048, vrbuf, ns);
            edge_logits_kernel<<<(NEDGE * NHEAD + 255) / 256, 256, 0, stream>>>(
                esrc[r], edst[r], qbuf[d], krbuf,
                p_rel + (size_t)(l * 4 + r) * NHEAD, alphabuf);
            seg_stats_kernel<<<((size_t)nd * NHEAD * 64 + 255) / 256, 256, 0, stream>>>(
                rowptr[r], elist[r], alphabuf, statsbuf, nd);
            seg_agg_kernel<<<(NEDGE + EPB - 1) / EPB, 128, 0, stream>>>(
                elist[r], esrc[r], edst[r], alphabuf, statsbuf, vrbuf, agg[d], NEDGE);
        }
        for (int t = 0; t < 3; t++) {
            int wi = l * 3 + t;
            gemm(agg[t], aw + (size_t)wi * 16384, abias + (size_t)wi * 128,
                 x[t], sizes[t], 128, 1, 0, x[t], skip, wi);
        }
    }

    // ---- output head ----
    gemm(x[0], w_out, b_out, (float*)d_out, NPAT, OUTN, 0, 2, nullptr, nullptr, 0);
}

// Round 3
// 2120.096 us; speedup vs baseline: 1.2089x; 1.2089x over previous
//
#include <hip/hip_runtime.h>
#include <math.h>

#define CDIM  128
#define NHEAD 8
#define DHEAD 16
#define NPAT  50000
#define NICD  591
#define NNDC  2042
#define OUTN  90
#define NEDGE 250000
#define NLAYER 2
#define EPB   128   // edges per block in seg_agg

__device__ __forceinline__ float gelu_tanh(float x) {
    float x3 = x * x * x;
    return 0.5f * x * (1.0f + tanhf(0.7978845608028654f * (x + 0.044715f * x3)));
}

// ---------------------------------------------------------------------------
// Generic fp32 GEMM: C = act(A[MxK=128] @ W[128xN] + bias), optional gelu on A
// load, optional learned-skip combine: C = a*o + (1-a)*xold, a=sigmoid(skip).
// Tile 64x64, 256 threads, 4x4 micro-tile per thread.
// ---------------------------------------------------------------------------
__global__ __launch_bounds__(256) void gemm_k128(
    const float* __restrict__ A, const float* __restrict__ W,
    const float* __restrict__ bias, float* __restrict__ Co,
    int M, int N, int gelu_in, int act,          // act: 0 none, 1 relu, 2 sigmoid
    const float* __restrict__ xold, const float* __restrict__ skipv, int skipidx)
{
    __shared__ float As[16][68];
    __shared__ float Ws[16][68];
    int bm = blockIdx.x * 64, bn = blockIdx.y * 64;
    int tl = threadIdx.x;
    int tx = tl & 15, ty = tl >> 4;
    float acc[4][4] = {};

    for (int k0 = 0; k0 < 128; k0 += 16) {
        {
            int am = tl >> 2;            // 0..63
            int ak = (tl & 3) * 4;       // 0,4,8,12
            int row = bm + am;
            float4 v = make_float4(0.f, 0.f, 0.f, 0.f);
            if (row < M) v = *(const float4*)(A + (size_t)row * 128 + k0 + ak);
            if (gelu_in) { v.x = gelu_tanh(v.x); v.y = gelu_tanh(v.y);
                           v.z = gelu_tanh(v.z); v.w = gelu_tanh(v.w); }
            As[ak + 0][am] = v.x; As[ak + 1][am] = v.y;
            As[ak + 2][am] = v.z; As[ak + 3][am] = v.w;
        }
        {
            int wk = tl >> 4;            // 0..15
            int wn = (tl & 15) * 4;      // 0..60
            int col = bn + wn;
            float4 v = make_float4(0.f, 0.f, 0.f, 0.f);
            const float* wp = W + (size_t)(k0 + wk) * N;
            if (((N & 3) == 0) && (col + 3) < N) {
                v = *(const float4*)(wp + col);
            } else {
                if (col     < N) v.x = wp[col];
                if (col + 1 < N) v.y = wp[col + 1];
                if (col + 2 < N) v.z = wp[col + 2];
                if (col + 3 < N) v.w = wp[col + 3];
            }
            Ws[wk][wn] = v.x; Ws[wk][wn + 1] = v.y;
            Ws[wk][wn + 2] = v.z; Ws[wk][wn + 3] = v.w;
        }
        __syncthreads();
        #pragma unroll
        for (int kk = 0; kk < 16; kk++) {
            float4 av = *(const float4*)&As[kk][ty * 4];
            float4 wv = *(const float4*)&Ws[kk][tx * 4];
            float a_[4] = {av.x, av.y, av.z, av.w};
            float w_[4] = {wv.x, wv.y, wv.z, wv.w};
            #pragma unroll
            for (int i = 0; i < 4; i++)
                #pragma unroll
                for (int j = 0; j < 4; j++)
                    acc[i][j] += a_[i] * w_[j];
        }
        __syncthreads();
    }

    float aSk = 0.f, oneM = 0.f;
    if (skipv) {
        float sv = skipv[skipidx];
        aSk = 1.0f / (1.0f + expf(-sv));
        oneM = 1.0f - aSk;
    }
    for (int i = 0; i < 4; i++) {
        int row = bm + ty * 4 + i;
        if (row >= M) break;
        for (int j = 0; j < 4; j++) {
            int col = bn + tx * 4 + j;
            if (col >= N) continue;
            float v = acc[i][j] + (bias ? bias[col] : 0.f);
            if (act == 1) v = fmaxf(v, 0.f);
            else if (act == 2) v = 1.0f / (1.0f + expf(-v));
            if (skipv) v = aSk * v + oneM * xold[(size_t)row * N + col];
            Co[(size_t)row * N + col] = v;
        }
    }
}

// ---------------------------------------------------------------------------
// CSR build: histogram, single-block exclusive scan, scatter (materializes
// src/dst in dst-sorted order so the edge pipeline never does an elist gather)
// ---------------------------------------------------------------------------
__global__ void hist_kernel(const int* __restrict__ dst, int* __restrict__ deg) {
    int t = blockIdx.x * blockDim.x + threadIdx.x;
    if (t < NEDGE) atomicAdd(&deg[dst[t]], 1);
}

__global__ __launch_bounds__(1024) void exscan_kernel(
    const int* __restrict__ in, int* __restrict__ out, int n)
{
    __shared__ int part[1024];
    int t = threadIdx.x;
    int per = (n + 1023) >> 10;
    int s0 = t * per, s1 = min(s0 + per, n);
    int s = 0;
    for (int i = s0; i < s1; i++) s += in[i];
    part[t] = s;
    __syncthreads();
    for (int off = 1; off < 1024; off <<= 1) {
        int v = (t >= off) ? part[t - off] : 0;
        __syncthreads();
        part[t] += v;
        __syncthreads();
    }
    int run = (t == 0) ? 0 : part[t - 1];
    for (int i = s0; i < s1; i++) { out[i] = run; run += in[i]; }
    if (t == 1023) out[n] = part[1023];
}

__global__ void scatter_kernel(const int* __restrict__ src,
                               const int* __restrict__ dst,
                               int* __restrict__ cursor,
                               int* __restrict__ src_s, int* __restrict__ dst_s) {
    int t = blockIdx.x * blockDim.x + threadIdx.x;
    if (t < NEDGE) {
        int d = dst[t];
        int p = atomicAdd(&cursor[d], 1);
        src_s[p] = src[t];
        dst_s[p] = d;
    }
}

// ---------------------------------------------------------------------------
// x = relu(emb[idx]) gather
// ---------------------------------------------------------------------------
__global__ void gather_relu_kernel(const float* __restrict__ emb,
                                   const int* __restrict__ idx,
                                   float* __restrict__ out, int n) {
    int t = blockIdx.x * blockDim.x + threadIdx.x;
    if (t < n * CDIM) {
        int r = t >> 7, c = t & 127;
        out[t] = fmaxf(emb[(size_t)idx[r] * CDIM + c], 0.f);
    }
}

// ---------------------------------------------------------------------------
// kr[n,h,e] = sum_d k[n,h,d] * arel[h,d,e]   (per-head 16x16 transform)
// 256 threads, 2 rows per barrier.
// ---------------------------------------------------------------------------
__global__ __launch_bounds__(256) void rel_transform_kernel(
    const float* __restrict__ kin, const float* __restrict__ arel,
    float* __restrict__ kout, int n)
{
    __shared__ float aS[NHEAD * DHEAD * DHEAD];   // 2048
    __shared__ float rowS[2][CDIM];
    int t = threadIdx.x;
    for (int i = t; i < NHEAD * DHEAD * DHEAD; i += 256) aS[i] = arel[i];
    __syncthreads();
    int rl = t >> 7;          // 0..1
    int c  = t & 127;
    int h = c >> 4, e = c & 15;
    const float* ah = &aS[h * 256 + e];
    for (int row0 = blockIdx.x * 2; row0 < n; row0 += gridDim.x * 2) {
        int row = row0 + rl;
        rowS[rl][c] = (row < n) ? kin[(size_t)row * CDIM + c] : 0.f;
        __syncthreads();
        float acc = 0.f;
        const float* rp = &rowS[rl][h * 16];
        #pragma unroll
        for (int dd = 0; dd < 16; ++dd) acc += rp[dd] * ah[dd * 16];
        if (row < n) kout[(size_t)row * CDIM + c] = acc;
        __syncthreads();
    }
}

// ---------------------------------------------------------------------------
// alpha_s[i,h] = (q[dst_s[i],h,:] . kr[src_s[i],h,:]) * p_rel[h] / sqrt(D)
// written directly in dst-sorted order.
// ---------------------------------------------------------------------------
__global__ __launch_bounds__(256) void edge_logits_kernel(
    const int* __restrict__ src_s, const int* __restrict__ dst_s,
    const float* __restrict__ q, const float* __restrict__ kr,
    const float* __restrict__ prel, float* __restrict__ alpha_s)
{
    int t = blockIdx.x * blockDim.x + threadIdx.x;
    if (t >= NEDGE * NHEAD) return;
    int i = t >> 3, h = t & 7;
    const float4* qp = (const float4*)(q  + (size_t)dst_s[i] * CDIM + h * DHEAD);
    const float4* kp = (const float4*)(kr + (size_t)src_s[i] * CDIM + h * DHEAD);
    float acc = 0.f;
    #pragma unroll
    for (int k = 0; k < 4; k++) {
        float4 a = qp[k], b = kp[k];
        acc += a.x * b.x + a.y * b.y + a.z * b.z + a.w * b.w;
    }
    alpha_s[t] = acc * prel[h] * 0.25f;
}

// ---------------------------------------------------------------------------
// Segment softmax stats: one WAVE per dst node, all 8 heads at once.
// lane = j*8+h reads alpha_s[(r0+j)*8+h] -> fully coalesced 256B per iter.
// Reduce across j (lane bits 3..5). stats[d*8+h] = {m, 1/s}.
// ---------------------------------------------------------------------------
__global__ __launch_bounds__(256) void seg_stats_kernel(
    const int* __restrict__ rowptr, const float* __restrict__ alpha_s,
    float2* __restrict__ stats, int nd)
{
    int wid = (blockIdx.x * 256 + threadIdx.x) >> 6;   // wave id == dst node
    int lane = threadIdx.x & 63;
    if (wid >= nd) return;
    int r0 = rowptr[wid], r1 = rowptr[wid + 1];
    int h = lane & 7, j = lane >> 3;
    float mx = -1e30f;
    for (int i = r0 + j; i < r1; i += 8)
        mx = fmaxf(mx, alpha_s[(size_t)i * NHEAD + h]);
    mx = fmaxf(mx, __shfl_xor(mx, 8));
    mx = fmaxf(mx, __shfl_xor(mx, 16));
    mx = fmaxf(mx, __shfl_xor(mx, 32));
    float sm = 0.f;
    for (int i = r0 + j; i < r1; i += 8)
        sm += expf(alpha_s[(size_t)i * NHEAD + h] - mx);
    sm += __shfl_xor(sm, 8);
    sm += __shfl_xor(sm, 16);
    sm += __shfl_xor(sm, 32);
    if (j == 0)
        stats[(size_t)wid * NHEAD + h] = make_float2(mx, (sm > 0.f) ? 1.0f / sm : 0.f);
}

// ---------------------------------------------------------------------------
// Edge-chunk-parallel weighted segment sum over dst-sorted edges. Staging
// threads read 8 weights with two float4 loads; 128 channel-threads accumulate
// per dst-run, flushing with atomicAdd only at run boundaries.
// ---------------------------------------------------------------------------
__global__ __launch_bounds__(128) void seg_agg_kernel(
    const int* __restrict__ src_s, const int* __restrict__ dst_s,
    const float* __restrict__ alpha_s, const float2* __restrict__ stats,
    const float* __restrict__ vr, float* __restrict__ agg, int ne)
{
    __shared__ int   sSrc[EPB];
    __shared__ int   sDst[EPB];
    __shared__ float sW[EPB][NHEAD];
    int i0 = blockIdx.x * EPB;
    int t  = threadIdx.x;
    int cnt = min(EPB, ne - i0);
    if (t < cnt) {
        int d = dst_s[i0 + t];
        sSrc[t] = src_s[i0 + t];
        sDst[t] = d;
        const float4* ap = (const float4*)(alpha_s + (size_t)(i0 + t) * NHEAD);
        float4 a0 = ap[0], a1 = ap[1];
        float w[8] = {a0.x, a0.y, a0.z, a0.w, a1.x, a1.y, a1.z, a1.w};
        const float2* st = stats + (size_t)d * NHEAD;
        #pragma unroll
        for (int h = 0; h < NHEAD; h++) {
            float2 ms = st[h];
            sW[t][h] = expf(w[h] - ms.x) * ms.y;
        }
    }
    __syncthreads();
    int h = t >> 4;
    float acc = 0.f;
    int curd = sDst[0];
    for (int i = 0; i < cnt; i++) {
        int d = sDst[i];
        if (d != curd) {
            atomicAdd(&agg[(size_t)curd * CDIM + t], acc);
            acc = 0.f;
            curd = d;
        }
        acc += vr[(size_t)sSrc[i] * CDIM + t] * sW[i][h];
    }
    atomicAdd(&agg[(size_t)curd * CDIM + t], acc);
}

// ---------------------------------------------------------------------------
extern "C" void kernel_launch(void* const* d_in, const int* in_sizes, int n_in,
                              void* d_out, int out_size, void* d_ws, size_t ws_size,
                              hipStream_t stream)
{
    const float* x_patient = (const float*)d_in[0];
    const float* w_in      = (const float*)d_in[1];
    const float* b_in      = (const float*)d_in[2];
    const float* emb_icd   = (const float*)d_in[3];
    const float* emb_ndc   = (const float*)d_in[4];
    const float* kw        = (const float*)d_in[5];
    const float* kbias     = (const float*)d_in[6];
    const float* qw        = (const float*)d_in[7];
    const float* qbias     = (const float*)d_in[8];
    const float* vw        = (const float*)d_in[9];
    const float* vbias     = (const float*)d_in[10];
    const float* aw        = (const float*)d_in[11];
    const float* abias     = (const float*)d_in[12];
    const float* skip      = (const float*)d_in[13];
    const float* a_rel     = (const float*)d_in[14];
    const float* m_rel     = (const float*)d_in[15];
    const float* p_rel     = (const float*)d_in[16];
    const float* w_out     = (const float*)d_in[17];
    const float* b_out     = (const float*)d_in[18];
    const int*   x_icd     = (const int*)d_in[19];
    const int*   x_ndc     = (const int*)d_in[20];
    const int* esrc[4] = {(const int*)d_in[21], (const int*)d_in[23],
                          (const int*)d_in[25], (const int*)d_in[27]};
    const int* edst[4] = {(const int*)d_in[22], (const int*)d_in[24],
                          (const int*)d_in[26], (const int*)d_in[28]};

    const int st_[4] = {0, 1, 0, 2};
    const int dt_[4] = {1, 0, 2, 0};
    const int sizes[3] = {NPAT, NICD, NNDC};

    char* p = (char*)d_ws;
    auto alloc = [&](size_t bytes) -> void* {
        void* r = (void*)p;
        p += (bytes + 255) & ~(size_t)255;
        return r;
    };

    float *x[3], *kbuf[3], *qbuf[3], *vbuf[3];
    for (int t = 0; t < 3; t++) x[t]    = (float*)alloc((size_t)sizes[t] * CDIM * 4);
    for (int t = 0; t < 3; t++) kbuf[t] = (float*)alloc((size_t)sizes[t] * CDIM * 4);
    for (int t = 0; t < 3; t++) qbuf[t] = (float*)alloc((size_t)sizes[t] * CDIM * 4);
    for (int t = 0; t < 3; t++) vbuf[t] = (float*)alloc((size_t)sizes[t] * CDIM * 4);
    float* aggbase = (float*)alloc((size_t)(NPAT + NICD + NNDC) * CDIM * 4);
    float* agg[3];
    agg[0] = aggbase;
    agg[1] = aggbase + (size_t)NPAT * CDIM;
    agg[2] = agg[1] + (size_t)NICD * CDIM;
    float*  krbuf    = (float*)alloc((size_t)NPAT * CDIM * 4);
    float*  vrbuf    = (float*)alloc((size_t)NPAT * CDIM * 4);
    float*  alphabuf = (float*)alloc((size_t)NEDGE * NHEAD * 4);
    float2* statsbuf = (float2*)alloc((size_t)NPAT * NHEAD * 8);
    int *rowptr[4], *srcS[4], *dstS[4];
    for (int r = 0; r < 4; r++) {
        rowptr[r] = (int*)alloc((size_t)(sizes[dt_[r]] + 1) * 4);
        srcS[r]   = (int*)alloc((size_t)NEDGE * 4);
        dstS[r]   = (int*)alloc((size_t)NEDGE * 4);
    }
    int* deg    = (int*)alloc((size_t)NPAT * 4);
    int* cursor = (int*)alloc((size_t)NPAT * 4);

    auto gemm = [&](const float* A, const float* W, const float* bias, float* Co,
                    int M, int N, int gelu_in, int act,
                    const float* xold, const float* skipv, int skipidx) {
        dim3 grid((M + 63) / 64, (N + 63) / 64);
        gemm_k128<<<grid, dim3(256), 0, stream>>>(A, W, bias, Co, M, N,
                                                  gelu_in, act, xold, skipv, skipidx);
    };

    // ---- CSR build (by dst), once per launch, reused by both layers ----
    for (int r = 0; r < 4; r++) {
        int nd = sizes[dt_[r]];
        hipMemsetAsync(deg, 0, (size_t)nd * 4, stream);
        hist_kernel<<<(NEDGE + 255) / 256, 256, 0, stream>>>(edst[r], deg);
        exscan_kernel<<<1, 1024, 0, stream>>>(deg, rowptr[r], nd);
        hipMemcpyAsync(cursor, rowptr[r], (size_t)nd * 4,
                       hipMemcpyDeviceToDevice, stream);
        scatter_kernel<<<(NEDGE + 255) / 256, 256, 0, stream>>>(
            esrc[r], edst[r], cursor, srcS[r], dstS[r]);
    }

    // ---- input projections ----
    gemm(x_patient, w_in, b_in, x[0], NPAT, 128, 0, 1, nullptr, nullptr, 0);
    gather_relu_kernel<<<(NICD * CDIM + 255) / 256, 256, 0, stream>>>(emb_icd, x_icd, x[1], NICD);
    gather_relu_kernel<<<(NNDC * CDIM + 255) / 256, 256, 0, stream>>>(emb_ndc, x_ndc, x[2], NNDC);

    // ---- layers ----
    for (int l = 0; l < NLAYER; l++) {
        for (int t = 0; t < 3; t++) {
            int wi = l * 3 + t;
            gemm(x[t], kw + (size_t)wi * 16384, kbias + (size_t)wi * 128,
                 kbuf[t], sizes[t], 128, 0, 0, nullptr, nullptr, 0);
            gemm(x[t], qw + (size_t)wi * 16384, qbias + (size_t)wi * 128,
                 qbuf[t], sizes[t], 128, 0, 0, nullptr, nullptr, 0);
            gemm(x[t], vw + (size_t)wi * 16384, vbias + (size_t)wi * 128,
                 vbuf[t], sizes[t], 128, 0, 0, nullptr, nullptr, 0);
        }
        hipMemsetAsync(aggbase, 0, (size_t)(NPAT + NICD + NNDC) * CDIM * 4, stream);
        for (int r = 0; r < 4; r++) {
            int s = st_[r], d = dt_[r];
            int ns = sizes[s], nd = sizes[d];
            int grid_rt = min((ns + 1) / 2, 2048);
            rel_transform_kernel<<<grid_rt, 256, 0, stream>>>(
                kbuf[s], a_rel + (size_t)(l * 4 + r) * 2048, krbuf, ns);
            rel_transform_kernel<<<grid_rt, 256, 0, stream>>>(
                vbuf[s], m_rel + (size_t)(l * 4 + r) * 2048, vrbuf, ns);
            edge_logits_kernel<<<(NEDGE * NHEAD + 255) / 256, 256, 0, stream>>>(
                srcS[r], dstS[r], qbuf[d], krbuf,
                p_rel + (size_t)(l * 4 + r) * NHEAD, alphabuf);
            seg_stats_kernel<<<(nd + 3) / 4, 256, 0, stream>>>(
                rowptr[r], alphabuf, statsbuf, nd);
            seg_agg_kernel<<<(NEDGE + EPB - 1) / EPB, 128, 0, stream>>>(
                srcS[r], dstS[r], alphabuf, statsbuf, vrbuf, agg[d], NEDGE);
        }
        for (int t = 0; t < 3; t++) {
            int wi = l * 3 + t;
            gemm(agg[t], aw + (size_t)wi * 16384, abias + (size_t)wi * 128,
                 x[t], sizes[t], 128, 1, 0, x[t], skip, wi);
        }
    }

    // ---- output head ----
    gemm(x[0], w_out, b_out, (float*)d_out, NPAT, OUTN, 0, 2, nullptr, nullptr, 0);
}

// Round 4
// 1892.997 us; speedup vs baseline: 1.3540x; 1.1200x over previous
//
#include <hip/hip_runtime.h>
#include <math.h>

#define CDIM  128
#define NHEAD 8
#define DHEAD 16
#define NPAT  50000
#define NICD  591
#define NNDC  2042
#define OUTN  90
#define NEDGE 250000
#define NLAYER 2
#define EPB   128   // edges per block in seg_agg

// concat offsets for CSR build (relation order: pi, ip, pn, np; dst sizes)
#define OFF0  0
#define OFF1  (NICD)
#define OFF2  (NICD + NPAT)
#define OFF3  (NICD + NPAT + NNDC)
#define NTOT  (NICD + NPAT + NNDC + NPAT)

__device__ __forceinline__ float gelu_tanh(float x) {
    float x3 = x * x * x;
    return 0.5f * x * (1.0f + tanhf(0.7978845608028654f * (x + 0.044715f * x3)));
}

// ---------------------------------------------------------------------------
// Generic fp32 GEMM: C = act(A[MxK=128] @ W[128xN] + bias), optional gelu on A
// load, optional learned-skip combine: C = a*o + (1-a)*xold, a=sigmoid(skip).
// Tile 64x64, 256 threads, 4x4 micro-tile per thread.
// ---------------------------------------------------------------------------
__global__ __launch_bounds__(256) void gemm_k128(
    const float* __restrict__ A, const float* __restrict__ W,
    const float* __restrict__ bias, float* __restrict__ Co,
    int M, int N, int gelu_in, int act,          // act: 0 none, 1 relu, 2 sigmoid
    const float* __restrict__ xold, const float* __restrict__ skipv, int skipidx)
{
    __shared__ float As[16][68];
    __shared__ float Ws[16][68];
    int bm = blockIdx.x * 64, bn = blockIdx.y * 64;
    int tl = threadIdx.x;
    int tx = tl & 15, ty = tl >> 4;
    float acc[4][4] = {};

    for (int k0 = 0; k0 < 128; k0 += 16) {
        {
            int am = tl >> 2;            // 0..63
            int ak = (tl & 3) * 4;       // 0,4,8,12
            int row = bm + am;
            float4 v = make_float4(0.f, 0.f, 0.f, 0.f);
            if (row < M) v = *(const float4*)(A + (size_t)row * 128 + k0 + ak);
            if (gelu_in) { v.x = gelu_tanh(v.x); v.y = gelu_tanh(v.y);
                           v.z = gelu_tanh(v.z); v.w = gelu_tanh(v.w); }
            As[ak + 0][am] = v.x; As[ak + 1][am] = v.y;
            As[ak + 2][am] = v.z; As[ak + 3][am] = v.w;
        }
        {
            int wk = tl >> 4;            // 0..15
            int wn = (tl & 15) * 4;      // 0..60
            int col = bn + wn;
            float4 v = make_float4(0.f, 0.f, 0.f, 0.f);
            const float* wp = W + (size_t)(k0 + wk) * N;
            if (((N & 3) == 0) && (col + 3) < N) {
                v = *(const float4*)(wp + col);
            } else {
                if (col     < N) v.x = wp[col];
                if (col + 1 < N) v.y = wp[col + 1];
                if (col + 2 < N) v.z = wp[col + 2];
                if (col + 3 < N) v.w = wp[col + 3];
            }
            Ws[wk][wn] = v.x; Ws[wk][wn + 1] = v.y;
            Ws[wk][wn + 2] = v.z; Ws[wk][wn + 3] = v.w;
        }
        __syncthreads();
        #pragma unroll
        for (int kk = 0; kk < 16; kk++) {
            float4 av = *(const float4*)&As[kk][ty * 4];
            float4 wv = *(const float4*)&Ws[kk][tx * 4];
            float a_[4] = {av.x, av.y, av.z, av.w};
            float w_[4] = {wv.x, wv.y, wv.z, wv.w};
            #pragma unroll
            for (int i = 0; i < 4; i++)
                #pragma unroll
                for (int j = 0; j < 4; j++)
                    acc[i][j] += a_[i] * w_[j];
        }
        __syncthreads();
    }

    float aSk = 0.f, oneM = 0.f;
    if (skipv) {
        float sv = skipv[skipidx];
        aSk = 1.0f / (1.0f + expf(-sv));
        oneM = 1.0f - aSk;
    }
    for (int i = 0; i < 4; i++) {
        int row = bm + ty * 4 + i;
        if (row >= M) break;
        for (int j = 0; j < 4; j++) {
            int col = bn + tx * 4 + j;
            if (col >= N) continue;
            float v = acc[i][j] + (bias ? bias[col] : 0.f);
            if (act == 1) v = fmaxf(v, 0.f);
            else if (act == 2) v = 1.0f / (1.0f + expf(-v));
            if (skipv) v = aSk * v + oneM * xold[(size_t)row * N + col];
            Co[(size_t)row * N + col] = v;
        }
    }
}

// ---------------------------------------------------------------------------
// Batched CSR build over all 4 relations in one concatenated degree array.
// Each relation has exactly NEDGE edges, so the concat exclusive scan S gives
// relation-local rowptr as S - r*NEDGE, and S itself is the scatter cursor
// into one 4*NEDGE dst-sorted edge array.
// ---------------------------------------------------------------------------
__global__ void hist4_kernel(const int* __restrict__ d0, const int* __restrict__ d1,
                             const int* __restrict__ d2, const int* __restrict__ d3,
                             int* __restrict__ deg) {
    int t = blockIdx.x * blockDim.x + threadIdx.x;
    if (t >= 4 * NEDGE) return;
    int r = t / NEDGE, e = t - r * NEDGE;
    const int* dp = (r == 0) ? d0 : (r == 1) ? d1 : (r == 2) ? d2 : d3;
    int off = (r == 0) ? OFF0 : (r == 1) ? OFF1 : (r == 2) ? OFF2 : OFF3;
    atomicAdd(&deg[off + dp[e]], 1);
}

// Phase A: per-1024-chunk sums (256 thr x 4 elems)
__global__ __launch_bounds__(256) void scanA_kernel(
    const int* __restrict__ deg, int* __restrict__ part, int n)
{
    __shared__ int red[256];
    int b = blockIdx.x, t = threadIdx.x;
    int base = b * 1024 + t * 4;
    int s = 0;
    if (base + 3 < n) {
        int4 v = *(const int4*)(deg + base);
        s = v.x + v.y + v.z + v.w;
    } else {
        for (int i = 0; i < 4; i++) if (base + i < n) s += deg[base + i];
    }
    red[t] = s;
    __syncthreads();
    for (int o = 128; o; o >>= 1) { if (t < o) red[t] += red[t + o]; __syncthreads(); }
    if (t == 0) part[b] = red[0];
}

// Phase B: exclusive scan of block partials (nb <= 256)
__global__ __launch_bounds__(128) void scanB_kernel(int* __restrict__ part, int nb)
{
    __shared__ int s[256];
    int t = threadIdx.x;
    for (int i = t; i < nb; i += 128) s[i] = part[i];
    __syncthreads();
    if (t == 0) { int run = 0; for (int i = 0; i < nb; i++) { int v = s[i]; s[i] = run; run += v; } }
    __syncthreads();
    for (int i = t; i < nb; i += 128) part[i] = s[i];
}

// Phase C: in-chunk exclusive scan + base; writes cursor (global S) and
// relation-local rowptrs (S - r*NEDGE).
__global__ __launch_bounds__(256) void scanC_kernel(
    const int* __restrict__ deg, const int* __restrict__ part,
    int* __restrict__ rp0, int* __restrict__ rp1,
    int* __restrict__ rp2, int* __restrict__ rp3,
    int* __restrict__ cursor, int n)
{
    __shared__ int red[256];
    int b = blockIdx.x, t = threadIdx.x;
    int base = b * 1024 + t * 4;
    int v[4] = {0, 0, 0, 0};
    if (base + 3 < n) {
        int4 q = *(const int4*)(deg + base);
        v[0] = q.x; v[1] = q.y; v[2] = q.z; v[3] = q.w;
    } else {
        for (int i = 0; i < 4; i++) if (base + i < n) v[i] = deg[base + i];
    }
    red[t] = v[0] + v[1] + v[2] + v[3];
    __syncthreads();
    for (int off = 1; off < 256; off <<= 1) {
        int y = (t >= off) ? red[t - off] : 0;
        __syncthreads();
        red[t] += y;
        __syncthreads();
    }
    int run = part[b] + ((t == 0) ? 0 : red[t - 1]);
    for (int i = 0; i < 4; i++) {
        int g = base + i;
        if (g < n) {
            cursor[g] = run;
            int r, loc;
            if      (g < OFF1) { r = 0; loc = g; }
            else if (g < OFF2) { r = 1; loc = g - OFF1; }
            else if (g < OFF3) { r = 2; loc = g - OFF2; }
            else               { r = 3; loc = g - OFF3; }
            int Sl = run - r * NEDGE;
            ((r == 0) ? rp0 : (r == 1) ? rp1 : (r == 2) ? rp2 : rp3)[loc] = Sl;
            run += v[i];
        }
    }
    if (b == 0 && t == 0) {
        rp0[NICD] = NEDGE; rp1[NPAT] = NEDGE; rp2[NNDC] = NEDGE; rp3[NPAT] = NEDGE;
    }
}

__global__ void scatter4_kernel(
    const int* __restrict__ s0, const int* __restrict__ d0,
    const int* __restrict__ s1, const int* __restrict__ d1,
    const int* __restrict__ s2, const int* __restrict__ d2,
    const int* __restrict__ s3, const int* __restrict__ d3,
    int* __restrict__ cursor, int* __restrict__ srcS, int* __restrict__ dstS)
{
    int t = blockIdx.x * blockDim.x + threadIdx.x;
    if (t >= 4 * NEDGE) return;
    int r = t / NEDGE, e = t - r * NEDGE;
    const int* sp = (r == 0) ? s0 : (r == 1) ? s1 : (r == 2) ? s2 : s3;
    const int* dp = (r == 0) ? d0 : (r == 1) ? d1 : (r == 2) ? d2 : d3;
    int off = (r == 0) ? OFF0 : (r == 1) ? OFF1 : (r == 2) ? OFF2 : OFF3;
    int d = dp[e];
    int p = atomicAdd(&cursor[off + d], 1);   // p already includes r*NEDGE base
    srcS[p] = sp[e];
    dstS[p] = d;
}

// ---------------------------------------------------------------------------
// x = relu(emb[idx]) gather
// ---------------------------------------------------------------------------
__global__ void gather_relu_kernel(const float* __restrict__ emb,
                                   const int* __restrict__ idx,
                                   float* __restrict__ out, int n) {
    int t = blockIdx.x * blockDim.x + threadIdx.x;
    if (t < n * CDIM) {
        int r = t >> 7, c = t & 127;
        out[t] = fmaxf(emb[(size_t)idx[r] * CDIM + c], 0.f);
    }
}

// ---------------------------------------------------------------------------
// kr[n,h,e] = sum_d k[n,h,d] * arel[h,d,e]   (per-head 16x16 transform)
// 256 threads, 2 rows per barrier.
// ---------------------------------------------------------------------------
__global__ __launch_bounds__(256) void rel_transform_kernel(
    const float* __restrict__ kin, const float* __restrict__ arel,
    float* __restrict__ kout, int n)
{
    __shared__ float aS[NHEAD * DHEAD * DHEAD];   // 2048
    __shared__ float rowS[2][CDIM];
    int t = threadIdx.x;
    for (int i = t; i < NHEAD * DHEAD * DHEAD; i += 256) aS[i] = arel[i];
    __syncthreads();
    int rl = t >> 7;          // 0..1
    int c  = t & 127;
    int h = c >> 4, e = c & 15;
    const float* ah = &aS[h * 256 + e];
    for (int row0 = blockIdx.x * 2; row0 < n; row0 += gridDim.x * 2) {
        int row = row0 + rl;
        rowS[rl][c] = (row < n) ? kin[(size_t)row * CDIM + c] : 0.f;
        __syncthreads();
        float acc = 0.f;
        const float* rp = &rowS[rl][h * 16];
        #pragma unroll
        for (int dd = 0; dd < 16; ++dd) acc += rp[dd] * ah[dd * 16];
        if (row < n) kout[(size_t)row * CDIM + c] = acc;
        __syncthreads();
    }
}

// ---------------------------------------------------------------------------
// alpha_s[i,h] = (q[dst_s[i],h,:] . kr[src_s[i],h,:]) * p_rel[h] / sqrt(D)
// written directly in dst-sorted order.
// ---------------------------------------------------------------------------
__global__ __launch_bounds__(256) void edge_logits_kernel(
    const int* __restrict__ src_s, const int* __restrict__ dst_s,
    const float* __restrict__ q, const float* __restrict__ kr,
    const float* __restrict__ prel, float* __restrict__ alpha_s)
{
    int t = blockIdx.x * blockDim.x + threadIdx.x;
    if (t >= NEDGE * NHEAD) return;
    int i = t >> 3, h = t & 7;
    const float4* qp = (const float4*)(q  + (size_t)dst_s[i] * CDIM + h * DHEAD);
    const float4* kp = (const float4*)(kr + (size_t)src_s[i] * CDIM + h * DHEAD);
    float acc = 0.f;
    #pragma unroll
    for (int k = 0; k < 4; k++) {
        float4 a = qp[k], b = kp[k];
        acc += a.x * b.x + a.y * b.y + a.z * b.z + a.w * b.w;
    }
    alpha_s[t] = acc * prel[h] * 0.25f;
}

// ---------------------------------------------------------------------------
// Segment softmax stats: one WAVE per dst node, all 8 heads at once.
// lane = j*8+h reads alpha_s[(r0+j)*8+h] -> fully coalesced 256B per iter.
// Reduce across j (lane bits 3..5). stats[d*8+h] = {m, 1/s}.
// ---------------------------------------------------------------------------
__global__ __launch_bounds__(256) void seg_stats_kernel(
    const int* __restrict__ rowptr, const float* __restrict__ alpha_s,
    float2* __restrict__ stats, int nd)
{
    int wid = (blockIdx.x * 256 + threadIdx.x) >> 6;   // wave id == dst node
    int lane = threadIdx.x & 63;
    if (wid >= nd) return;
    int r0 = rowptr[wid], r1 = rowptr[wid + 1];
    int h = lane & 7, j = lane >> 3;
    float mx = -1e30f;
    for (int i = r0 + j; i < r1; i += 8)
        mx = fmaxf(mx, alpha_s[(size_t)i * NHEAD + h]);
    mx = fmaxf(mx, __shfl_xor(mx, 8));
    mx = fmaxf(mx, __shfl_xor(mx, 16));
    mx = fmaxf(mx, __shfl_xor(mx, 32));
    float sm = 0.f;
    for (int i = r0 + j; i < r1; i += 8)
        sm += expf(alpha_s[(size_t)i * NHEAD + h] - mx);
    sm += __shfl_xor(sm, 8);
    sm += __shfl_xor(sm, 16);
    sm += __shfl_xor(sm, 32);
    if (j == 0)
        stats[(size_t)wid * NHEAD + h] = make_float2(mx, (sm > 0.f) ? 1.0f / sm : 0.f);
}

// ---------------------------------------------------------------------------
// Edge-chunk-parallel weighted segment sum over dst-sorted edges. Staging
// threads read 8 weights with two float4 loads; 128 channel-threads accumulate
// per dst-run, flushing with atomicAdd only at run boundaries.
// ---------------------------------------------------------------------------
__global__ __launch_bounds__(128) void seg_agg_kernel(
    const int* __restrict__ src_s, const int* __restrict__ dst_s,
    const float* __restrict__ alpha_s, const float2* __restrict__ stats,
    const float* __restrict__ vr, float* __restrict__ agg, int ne)
{
    __shared__ int   sSrc[EPB];
    __shared__ int   sDst[EPB];
    __shared__ float sW[EPB][NHEAD];
    int i0 = blockIdx.x * EPB;
    int t  = threadIdx.x;
    int cnt = min(EPB, ne - i0);
    if (t < cnt) {
        int d = dst_s[i0 + t];
        sSrc[t] = src_s[i0 + t];
        sDst[t] = d;
        const float4* ap = (const float4*)(alpha_s + (size_t)(i0 + t) * NHEAD);
        float4 a0 = ap[0], a1 = ap[1];
        float w[8] = {a0.x, a0.y, a0.z, a0.w, a1.x, a1.y, a1.z, a1.w};
        const float2* st = stats + (size_t)d * NHEAD;
        #pragma unroll
        for (int h = 0; h < NHEAD; h++) {
            float2 ms = st[h];
            sW[t][h] = expf(w[h] - ms.x) * ms.y;
        }
    }
    __syncthreads();
    int h = t >> 4;
    float acc = 0.f;
    int curd = sDst[0];
    for (int i = 0; i < cnt; i++) {
        int d = sDst[i];
        if (d != curd) {
            atomicAdd(&agg[(size_t)curd * CDIM + t], acc);
            acc = 0.f;
            curd = d;
        }
        acc += vr[(size_t)sSrc[i] * CDIM + t] * sW[i][h];
    }
    atomicAdd(&agg[(size_t)curd * CDIM + t], acc);
}

// ---------------------------------------------------------------------------
extern "C" void kernel_launch(void* const* d_in, const int* in_sizes, int n_in,
                              void* d_out, int out_size, void* d_ws, size_t ws_size,
                              hipStream_t stream)
{
    const float* x_patient = (const float*)d_in[0];
    const float* w_in      = (const float*)d_in[1];
    const float* b_in      = (const float*)d_in[2];
    const float* emb_icd   = (const float*)d_in[3];
    const float* emb_ndc   = (const float*)d_in[4];
    const float* kw        = (const float*)d_in[5];
    const float* kbias     = (const float*)d_in[6];
    const float* qw        = (const float*)d_in[7];
    const float* qbias     = (const float*)d_in[8];
    const float* vw        = (const float*)d_in[9];
    const float* vbias     = (const float*)d_in[10];
    const float* aw        = (const float*)d_in[11];
    const float* abias     = (const float*)d_in[12];
    const float* skip      = (const float*)d_in[13];
    const float* a_rel     = (const float*)d_in[14];
    const float* m_rel     = (const float*)d_in[15];
    const float* p_rel     = (const float*)d_in[16];
    const float* w_out     = (const float*)d_in[17];
    const float* b_out     = (const float*)d_in[18];
    const int*   x_icd     = (const int*)d_in[19];
    const int*   x_ndc     = (const int*)d_in[20];
    const int* esrc[4] = {(const int*)d_in[21], (const int*)d_in[23],
                          (const int*)d_in[25], (const int*)d_in[27]};
    const int* edst[4] = {(const int*)d_in[22], (const int*)d_in[24],
                          (const int*)d_in[26], (const int*)d_in[28]};

    const int st_[4] = {0, 1, 0, 2};
    const int dt_[4] = {1, 0, 2, 0};
    const int sizes[3] = {NPAT, NICD, NNDC};

    char* p = (char*)d_ws;
    auto alloc = [&](size_t bytes) -> void* {
        void* r = (void*)p;
        p += (bytes + 255) & ~(size_t)255;
        return r;
    };

    float *x[3], *kbuf[3], *qbuf[3], *vbuf[3];
    for (int t = 0; t < 3; t++) x[t]    = (float*)alloc((size_t)sizes[t] * CDIM * 4);
    for (int t = 0; t < 3; t++) kbuf[t] = (float*)alloc((size_t)sizes[t] * CDIM * 4);
    for (int t = 0; t < 3; t++) qbuf[t] = (float*)alloc((size_t)sizes[t] * CDIM * 4);
    for (int t = 0; t < 3; t++) vbuf[t] = (float*)alloc((size_t)sizes[t] * CDIM * 4);
    float* aggbase = (float*)alloc((size_t)(NPAT + NICD + NNDC) * CDIM * 4);
    float* agg[3];
    agg[0] = aggbase;
    agg[1] = aggbase + (size_t)NPAT * CDIM;
    agg[2] = agg[1] + (size_t)NICD * CDIM;
    float*  krbuf    = (float*)alloc((size_t)NPAT * CDIM * 4);
    float*  vrbuf    = (float*)alloc((size_t)NPAT * CDIM * 4);
    float*  alphabuf = (float*)alloc((size_t)NEDGE * NHEAD * 4);
    float2* statsbuf = (float2*)alloc((size_t)NPAT * NHEAD * 8);
    int* srcSbig = (int*)alloc((size_t)4 * NEDGE * 4);
    int* dstSbig = (int*)alloc((size_t)4 * NEDGE * 4);
    int* rowptr[4];
    rowptr[0] = (int*)alloc((size_t)(NICD + 1) * 4);
    rowptr[1] = (int*)alloc((size_t)(NPAT + 1) * 4);
    rowptr[2] = (int*)alloc((size_t)(NNDC + 1) * 4);
    rowptr[3] = (int*)alloc((size_t)(NPAT + 1) * 4);
    int* deg    = (int*)alloc((size_t)NTOT * 4);
    int* cursor = (int*)alloc((size_t)NTOT * 4);
    int* part   = (int*)alloc((size_t)256 * 4);
    int* srcS[4], *dstS[4];
    for (int r = 0; r < 4; r++) {
        srcS[r] = srcSbig + (size_t)r * NEDGE;
        dstS[r] = dstSbig + (size_t)r * NEDGE;
    }

    auto gemm = [&](const float* A, const float* W, const float* bias, float* Co,
                    int M, int N, int gelu_in, int act,
                    const float* xold, const float* skipv, int skipidx) {
        dim3 grid((M + 63) / 64, (N + 63) / 64);
        gemm_k128<<<grid, dim3(256), 0, stream>>>(A, W, bias, Co, M, N,
                                                  gelu_in, act, xold, skipv, skipidx);
    };

    // ---- batched CSR build (by dst), once per launch, reused by both layers ----
    {
        const int NB = (NTOT + 1023) / 1024;   // 101
        hipMemsetAsync(deg, 0, (size_t)NTOT * 4, stream);
        hist4_kernel<<<(4 * NEDGE + 255) / 256, 256, 0, stream>>>(
            edst[0], edst[1], edst[2], edst[3], deg);
        scanA_kernel<<<NB, 256, 0, stream>>>(deg, part, NTOT);
        scanB_kernel<<<1, 128, 0, stream>>>(part, NB);
        scanC_kernel<<<NB, 256, 0, stream>>>(deg, part,
            rowptr[0], rowptr[1], rowptr[2], rowptr[3], cursor, NTOT);
        scatter4_kernel<<<(4 * NEDGE + 255) / 256, 256, 0, stream>>>(
            esrc[0], edst[0], esrc[1], edst[1], esrc[2], edst[2], esrc[3], edst[3],
            cursor, srcSbig, dstSbig);
    }

    // ---- input projections ----
    gemm(x_patient, w_in, b_in, x[0], NPAT, 128, 0, 1, nullptr, nullptr, 0);
    gather_relu_kernel<<<(NICD * CDIM + 255) / 256, 256, 0, stream>>>(emb_icd, x_icd, x[1], NICD);
    gather_relu_kernel<<<(NNDC * CDIM + 255) / 256, 256, 0, stream>>>(emb_ndc, x_ndc, x[2], NNDC);

    // ---- layers ----
    for (int l = 0; l < NLAYER; l++) {
        for (int t = 0; t < 3; t++) {
            int wi = l * 3 + t;
            gemm(x[t], kw + (size_t)wi * 16384, kbias + (size_t)wi * 128,
                 kbuf[t], sizes[t], 128, 0, 0, nullptr, nullptr, 0);
            gemm(x[t], qw + (size_t)wi * 16384, qbias + (size_t)wi * 128,
                 qbuf[t], sizes[t], 128, 0, 0, nullptr, nullptr, 0);
            gemm(x[t], vw + (size_t)wi * 16384, vbias + (size_t)wi * 128,
                 vbuf[t], sizes[t], 128, 0, 0, nullptr, nullptr, 0);
        }
        hipMemsetAsync(aggbase, 0, (size_t)(NPAT + NICD + NNDC) * CDIM * 4, stream);
        for (int r = 0; r < 4; r++) {
            int s = st_[r], d = dt_[r];
            int ns = sizes[s], nd = sizes[d];
            int grid_rt = min((ns + 1) / 2, 2048);
            rel_transform_kernel<<<grid_rt, 256, 0, stream>>>(
                kbuf[s], a_rel + (size_t)(l * 4 + r) * 2048, krbuf, ns);
            rel_transform_kernel<<<grid_rt, 256, 0, stream>>>(
                vbuf[s], m_rel + (size_t)(l * 4 + r) * 2048, vrbuf, ns);
            edge_logits_kernel<<<(NEDGE * NHEAD + 255) / 256, 256, 0, stream>>>(
                srcS[r], dstS[r], qbuf[d], krbuf,
                p_rel + (size_t)(l * 4 + r) * NHEAD, alphabuf);
            seg_stats_kernel<<<(nd + 3) / 4, 256, 0, stream>>>(
                rowptr[r], alphabuf, statsbuf, nd);
            seg_agg_kernel<<<(NEDGE + EPB - 1) / EPB, 128, 0, stream>>>(
                srcS[r], dstS[r], alphabuf, statsbuf, vrbuf, agg[d], NEDGE);
        }
        for (int t = 0; t < 3; t++) {
            int wi = l * 3 + t;
            gemm(agg[t], aw + (size_t)wi * 16384, abias + (size_t)wi * 128,
                 x[t], sizes[t], 128, 1, 0, x[t], skip, wi);
        }
    }

    // ---- output head ----
    gemm(x[0], w_out, b_out, (float*)d_out, NPAT, OUTN, 0, 2, nullptr, nullptr, 0);
}